// Round 2
// baseline (11812.604 us; speedup 1.0000x reference)
//
#include <hip/hip_runtime.h>
#include <hip/hip_bf16.h>
#include <math.h>

namespace {

constexpr int Bb   = 16;
constexpr int Cc   = 128;
constexpr int Tt   = 294;
constexpr int Vv   = 25;
constexpr int TV   = Tt * Vv;        // 7350
constexpr int NPOS = Bb * TV;        // 117600
constexpr int INNER = 512;
constexpr int HID   = 512;
constexpr int NH    = 8;
constexpr int DH    = 64;
constexpr int Pp    = 7;             // local patch
constexpr int Kk    = 7;             // global kv stride
constexpr int NT    = 42;            // T / P
constexpr int TK    = 42;            // T / K
constexpr float EPS   = 1e-5f;
constexpr float SCALE = 0.125f;      // 64^-0.5
constexpr int FR = 20;               // ff rows per block (117600 = 20*5880)

// ---------- batched transpose: src (M x N) -> dst (N x M), z = batch ----------
__global__ __launch_bounds__(256) void k_transpose(const float* __restrict__ src,
                                                   float* __restrict__ dst,
                                                   int M, int N) {
  __shared__ float tile[32][33];
  size_t off = (size_t)blockIdx.z * (size_t)M * (size_t)N;
  src += off; dst += off;
  int bx = blockIdx.x * 32, by = blockIdx.y * 32;
  int tx = threadIdx.x, ty = threadIdx.y;   // (32, 8)
#pragma unroll
  for (int r = 0; r < 4; ++r) {
    int row = by + ty + r * 8, col = bx + tx;
    if (row < M && col < N) tile[ty + r * 8][tx] = src[(size_t)row * N + col];
  }
  __syncthreads();
#pragma unroll
  for (int r = 0; r < 4; ++r) {
    int row = bx + ty + r * 8, col = by + tx;
    if (row < N && col < M) dst[(size_t)row * M + col] = tile[tx][ty + r * 8];
  }
}

// ---------- per-position LN stats over C (mean, rstd) ----------
__global__ __launch_bounds__(256) void k_stats(const float* __restrict__ xT,
                                               float* __restrict__ mean,
                                               float* __restrict__ rstd) {
  int row  = blockIdx.x * 4 + (threadIdx.x >> 6);
  int lane = threadIdx.x & 63;
  const float* p = xT + (size_t)row * Cc;
  float a = p[lane], b = p[lane + 64];
  float s = a + b, ss = a * a + b * b;
#pragma unroll
  for (int off = 32; off; off >>= 1) {
    s  += __shfl_xor(s, off);
    ss += __shfl_xor(ss, off);
  }
  if (lane == 0) {
    float m = s * (1.0f / Cc);
    mean[row] = m;
    rstd[row] = rsqrtf(ss * (1.0f / Cc) - m * m + EPS);
  }
}

// ---------- fused local attention: one block per (b, patch, v) ----------
__global__ __launch_bounds__(256) void k_local(float* __restrict__ xT,
                                               const float* __restrict__ mean,
                                               const float* __restrict__ rstd,
                                               const float* __restrict__ g,
                                               const float* __restrict__ be,
                                               const float* __restrict__ wq,
                                               const float* __restrict__ wkv,
                                               const float* __restrict__ wo,
                                               const float* __restrict__ bo) {
  __shared__ float xs[Pp][Cc];          // original rows (residual)
  __shared__ float xn[Pp][Cc];          // normed rows
  __shared__ float qkv[Pp][3 * INNER];  // q | k | v ; q region reused for o
  __shared__ float att[NH][Pp][Pp];
  __shared__ float pbuf[2][Pp][Cc];     // proj partials (dedicated — was the bug)

  int bid = blockIdx.x;
  int v   = bid % Vv;
  int ntb = (bid / Vv) % NT;
  int b   = bid / (Vv * NT);
  int tid = threadIdx.x;
  int t0  = ntb * Pp;

  for (int e = tid; e < Pp * Cc; e += 256) {
    int p = e >> 7, c = e & 127;
    int row = (b * Tt + t0 + p) * Vv + v;
    float val = xT[(size_t)row * Cc + c];
    xs[p][c] = val;
    xn[p][c] = (val - mean[row]) * rstd[row] * g[c] + be[c];
  }
  __syncthreads();

  // q,k,v = xn @ [wq | wkv]
  for (int col = tid; col < 3 * INNER; col += 256) {
    const float* wp; int stride, ccol;
    if (col < INNER) { wp = wq;  stride = INNER;     ccol = col; }
    else             { wp = wkv; stride = 2 * INNER; ccol = col - INNER; }
    float acc[Pp];
#pragma unroll
    for (int p = 0; p < Pp; ++p) acc[p] = 0.f;
    for (int c = 0; c < Cc; ++c) {
      float wv = wp[(size_t)c * stride + ccol];
#pragma unroll
      for (int p = 0; p < Pp; ++p) acc[p] += xn[p][c] * wv;
    }
#pragma unroll
    for (int p = 0; p < Pp; ++p) qkv[p][col] = acc[p];
  }
  __syncthreads();

  // dots
  for (int e = tid; e < NH * Pp * Pp; e += 256) {
    int h = e / (Pp * Pp), r = e % (Pp * Pp);
    int i = r / Pp, j = r % Pp;
    float acc = 0.f;
#pragma unroll 16
    for (int d = 0; d < DH; ++d)
      acc += qkv[i][h * DH + d] * qkv[j][INNER + h * DH + d];
    att[h][i][j] = acc * SCALE;
  }
  __syncthreads();

  // softmax rows (56 rows of 7)
  for (int rr = tid; rr < NH * Pp; rr += 256) {
    int h = rr / Pp, i = rr % Pp;
    float mx = att[h][i][0];
#pragma unroll
    for (int j = 1; j < Pp; ++j) mx = fmaxf(mx, att[h][i][j]);
    float ev[Pp], sum = 0.f;
#pragma unroll
    for (int j = 0; j < Pp; ++j) { ev[j] = expf(att[h][i][j] - mx); sum += ev[j]; }
    float inv = 1.0f / sum;
#pragma unroll
    for (int j = 0; j < Pp; ++j) att[h][i][j] = ev[j] * inv;
  }
  __syncthreads();

  // o = att @ v  (overwrite q region)
  for (int e = tid; e < Pp * INNER; e += 256) {
    int p = e >> 9, i = e & 511, h = i >> 6;
    float acc = 0.f;
#pragma unroll
    for (int j = 0; j < Pp; ++j) acc += att[h][p][j] * qkv[j][2 * INNER + i];
    qkv[p][i] = acc;
  }
  __syncthreads();

  // proj: split i-range over two half-blocks, partials into pbuf
  {
    int co = tid & 127, ih = tid >> 7;
    float acc[Pp];
#pragma unroll
    for (int p = 0; p < Pp; ++p) acc[p] = 0.f;
    for (int i = ih * 256; i < ih * 256 + 256; ++i) {
      float wv = wo[(size_t)i * Cc + co];
#pragma unroll
      for (int p = 0; p < Pp; ++p) acc[p] += qkv[p][i] * wv;
    }
#pragma unroll
    for (int p = 0; p < Pp; ++p) pbuf[ih][p][co] = acc[p];
  }
  __syncthreads();
  for (int e = tid; e < Pp * Cc; e += 256) {
    int p = e >> 7, co = e & 127;
    int row = (b * Tt + t0 + p) * Vv + v;
    float s = bo[co] + xs[p][co] + pbuf[0][p][co] + pbuf[1][p][co];
    xT[(size_t)row * Cc + co] = s;
  }
}

// ---------- fused feed-forward: FR rows per block ----------
__global__ __launch_bounds__(256) void k_ff(float* __restrict__ xT,
                                            const float* __restrict__ mean,
                                            const float* __restrict__ rstd,
                                            const float* __restrict__ g,
                                            const float* __restrict__ be,
                                            const float* __restrict__ w1,
                                            const float* __restrict__ b1,
                                            const float* __restrict__ w2,
                                            const float* __restrict__ b2) {
  __shared__ float xn[FR][Cc];
  __shared__ float hb[FR][HID];   // hidden; later reused for partials (5120 <= 10240 ok)
  int tid = threadIdx.x;
  int row0 = blockIdx.x * FR;

  for (int e = tid; e < FR * Cc; e += 256) {
    int r = e >> 7, c = e & 127;
    int row = row0 + r;
    float val = xT[(size_t)row * Cc + c];
    xn[r][c] = (val - mean[row]) * rstd[row] * g[c] + be[c];
  }
  __syncthreads();

  for (int col = tid; col < HID; col += 256) {
    float acc[FR];
#pragma unroll
    for (int r = 0; r < FR; ++r) acc[r] = 0.f;
    for (int c = 0; c < Cc; ++c) {
      float wv = w1[(size_t)c * HID + col];
#pragma unroll
      for (int r = 0; r < FR; ++r) acc[r] += xn[r][c] * wv;
    }
    float bb = b1[col];
#pragma unroll
    for (int r = 0; r < FR; ++r) {
      float xv = acc[r] + bb;
      hb[r][col] = 0.5f * xv * (1.0f + erff(xv * 0.70710678118654752f));
    }
  }
  __syncthreads();

  // out GEMM: split hidden over two half-blocks, partials back into hb
  {
    int co = tid & 127, ih = tid >> 7;
    float acc[FR];
#pragma unroll
    for (int r = 0; r < FR; ++r) acc[r] = 0.f;
    for (int j = ih * 256; j < ih * 256 + 256; ++j) {
      float wv = w2[(size_t)j * Cc + co];
#pragma unroll
      for (int r = 0; r < FR; ++r) acc[r] += hb[r][j] * wv;
    }
    __syncthreads();   // all hb reads done before overwrite
    float* part = &hb[0][0];
#pragma unroll
    for (int r = 0; r < FR; ++r) part[ih * (FR * Cc) + r * Cc + co] = acc[r];
  }
  __syncthreads();
  {
    const float* part = &hb[0][0];
    for (int e = tid; e < FR * Cc; e += 256) {
      int r = e >> 7, co = e & 127;
      int row = row0 + r;
      float s = b2[co] + xT[(size_t)row * Cc + co] + part[r * Cc + co] + part[FR * Cc + r * Cc + co];
      xT[(size_t)row * Cc + co] = s;
    }
  }
}

// ---------- global attention: kv blocked conv, one block per (b, v, third) ----------
__global__ __launch_bounds__(256) void k_gkv(const float* __restrict__ xT,
                                             const float* __restrict__ mean,
                                             const float* __restrict__ rstd,
                                             const float* __restrict__ g,
                                             const float* __restrict__ be,
                                             const float* __restrict__ wkv,
                                             float* __restrict__ kvg) {
  __shared__ float xs[98][Cc];   // 98 = 14 j-blocks * 7
  int bid = blockIdx.x;
  int jh = bid % 3;
  int v  = (bid / 3) % Vv;
  int b  = bid / (3 * Vv);
  int tid = threadIdx.x;
  int tl0 = jh * 98;

  for (int e = tid; e < 98 * Cc; e += 256) {
    int r = e >> 7, c = e & 127;
    int row = (b * Tt + tl0 + r) * Vv + v;
    float val = xT[(size_t)row * Cc + c];
    xs[r][c] = (val - mean[row]) * rstd[row] * g[c] + be[c];
  }
  __syncthreads();

  int j0 = jh * 14;
  for (int col = tid; col < 2 * INNER; col += 256) {
    float acc[14];
#pragma unroll
    for (int j = 0; j < 14; ++j) acc[j] = 0.f;
    for (int kk = 0; kk < Kk; ++kk) {
      for (int c = 0; c < Cc; ++c) {
        float wv = wkv[((size_t)c * Kk + kk) * (2 * INNER) + col];
#pragma unroll
        for (int j = 0; j < 14; ++j) acc[j] += xs[j * 7 + kk][c] * wv;
      }
    }
#pragma unroll
    for (int j = 0; j < 14; ++j)
      kvg[((size_t)(b * Vv + v) * TK + j0 + j) * (2 * INNER) + col] = acc[j];
  }
}

// ---------- global attention: fused q + attn + proj, one block per (b, v, t-tile) ----------
__global__ __launch_bounds__(256) void k_gattn(float* __restrict__ xT,
                                               const float* __restrict__ mean,
                                               const float* __restrict__ rstd,
                                               const float* __restrict__ g,
                                               const float* __restrict__ be,
                                               const float* __restrict__ wq,
                                               const float* __restrict__ kvg,
                                               const float* __restrict__ wo,
                                               const float* __restrict__ bo) {
  constexpr int TTt = 32;
  __shared__ float xn[TTt][Cc];
  __shared__ __align__(16) __hip_bfloat16 qo[TTt][INNER];  // q then o; also proj partials (8192 f exactly)

  int bid = blockIdx.x;
  int tt = bid % 10;
  int v  = (bid / 10) % Vv;
  int b  = bid / (10 * Vv);
  int tid = threadIdx.x;
  int t0 = tt * TTt;
  int nT = (Tt - t0 < TTt) ? (Tt - t0) : TTt;   // 32 or 6

  for (int e = tid; e < TTt * Cc; e += 256) {
    int r = e >> 7, c = e & 127;
    float val = 0.f;
    if (r < nT) {
      int row = (b * Tt + t0 + r) * Vv + v;
      float xv = xT[(size_t)row * Cc + c];
      val = (xv - mean[row]) * rstd[row] * g[c] + be[c];
    }
    xn[r][c] = val;
  }
  __syncthreads();

  // q = xn @ wq
  for (int col = tid; col < INNER; col += 256) {
    float acc[TTt];
#pragma unroll
    for (int r = 0; r < TTt; ++r) acc[r] = 0.f;
    for (int c = 0; c < Cc; ++c) {
      float wv = wq[(size_t)c * INNER + col];
#pragma unroll
      for (int r = 0; r < TTt; ++r) acc[r] += xn[r][c] * wv;
    }
#pragma unroll
    for (int r = 0; r < TTt; ++r) qo[r][col] = __float2bfloat16(acc[r]);
  }
  __syncthreads();

  // attention: thread = (head, t-local)
  int h = tid >> 5, tl = tid & 31;
  float s[TK];
  const float* kbase = kvg + (size_t)(b * Vv + v) * TK * (2 * INNER) + h * DH;
  if (tl < nT) {
#pragma unroll
    for (int j = 0; j < TK; ++j) {
      float acc = 0.f;
#pragma unroll 16
      for (int d = 0; d < DH; ++d)
        acc += __bfloat162float(qo[tl][h * DH + d]) * kbase[(size_t)j * (2 * INNER) + d];
      s[j] = acc * SCALE;
    }
    float mx = s[0];
#pragma unroll
    for (int j = 1; j < TK; ++j) mx = fmaxf(mx, s[j]);
    float sum = 0.f;
#pragma unroll
    for (int j = 0; j < TK; ++j) { s[j] = expf(s[j] - mx); sum += s[j]; }
    float inv = 1.0f / sum;
#pragma unroll
    for (int j = 0; j < TK; ++j) s[j] *= inv;
  }
  __syncthreads();   // dots all done reading q before o overwrites it
  if (tl < nT) {
    const float* vbase = kbase + INNER;
#pragma unroll 8
    for (int d = 0; d < DH; ++d) {
      float acc = 0.f;
#pragma unroll
      for (int j = 0; j < TK; ++j) acc += s[j] * vbase[(size_t)j * (2 * INNER) + d];
      qo[tl][h * DH + d] = __float2bfloat16(acc);
    }
  }
  __syncthreads();

  // proj + residual: split INNER over two half-blocks
  {
    int co = tid & 127, ih = tid >> 7;
    float acc[TTt];
#pragma unroll
    for (int r = 0; r < TTt; ++r) acc[r] = 0.f;
    for (int i = ih * 256; i < ih * 256 + 256; ++i) {
      float wv = wo[(size_t)i * Cc + co];
#pragma unroll
      for (int r = 0; r < TTt; ++r) acc[r] += __bfloat162float(qo[r][i]) * wv;
    }
    __syncthreads();   // all qo reads done before overwrite
    float* part = (float*)&qo[0][0];   // 8192-float capacity
#pragma unroll
    for (int r = 0; r < TTt; ++r) part[ih * (TTt * Cc) + r * Cc + co] = acc[r];
  }
  __syncthreads();
  {
    const float* part = (const float*)&qo[0][0];
    for (int e = tid; e < nT * Cc; e += 256) {
      int r = e >> 7, co = e & 127;
      int row = (b * Tt + t0 + r) * Vv + v;
      float sres = bo[co] + xT[(size_t)row * Cc + co] + part[r * Cc + co] + part[TTt * Cc + r * Cc + co];
      xT[(size_t)row * Cc + co] = sres;
    }
  }
}

}  // namespace

extern "C" void kernel_launch(void* const* d_in, const int* in_sizes, int n_in,
                              void* d_out, int out_size, void* d_ws, size_t ws_size,
                              hipStream_t stream) {
  const float* x      = (const float*)d_in[0];
  const float* ln1_g  = (const float*)d_in[1];
  const float* ln1_b  = (const float*)d_in[2];
  const float* la_wq  = (const float*)d_in[3];
  const float* la_wkv = (const float*)d_in[4];
  const float* la_wo  = (const float*)d_in[5];
  const float* la_bo  = (const float*)d_in[6];
  const float* ln2_g  = (const float*)d_in[7];
  const float* ln2_b  = (const float*)d_in[8];
  const float* ff1_w1 = (const float*)d_in[9];
  const float* ff1_b1 = (const float*)d_in[10];
  const float* ff1_w2 = (const float*)d_in[11];
  const float* ff1_b2 = (const float*)d_in[12];
  const float* ln3_g  = (const float*)d_in[13];
  const float* ln3_b  = (const float*)d_in[14];
  const float* ga_wq  = (const float*)d_in[15];
  const float* ga_wkv = (const float*)d_in[16];
  const float* ga_wo  = (const float*)d_in[17];
  const float* ga_bo  = (const float*)d_in[18];
  const float* ln4_g  = (const float*)d_in[19];
  const float* ln4_b  = (const float*)d_in[20];
  const float* ff2_w1 = (const float*)d_in[21];
  const float* ff2_b1 = (const float*)d_in[22];
  const float* ff2_w2 = (const float*)d_in[23];
  const float* ff2_b2 = (const float*)d_in[24];

  float* xT   = (float*)d_ws;                       // NPOS*Cc
  float* mean = xT + (size_t)NPOS * Cc;             // NPOS
  float* rstd = mean + NPOS;                        // NPOS
  float* kvg  = rstd + NPOS;                        // Bb*Vv*TK*1024

  dim3 blk2(32, 8);
  // x (B,C,T,V) -> xT position-major (b,t,v) x C
  hipLaunchKernelGGL(k_transpose, dim3((TV + 31) / 32, (Cc + 31) / 32, Bb), blk2, 0, stream,
                     x, xT, Cc, TV);

  for (int i = 0; i < 2; ++i) {
    hipLaunchKernelGGL(k_stats, dim3(NPOS / 4), dim3(256), 0, stream, xT, mean, rstd);
    hipLaunchKernelGGL(k_local, dim3(Bb * NT * Vv), dim3(256), 0, stream,
                       xT, mean, rstd, ln1_g + i * Cc, ln1_b + i * Cc,
                       la_wq + (size_t)i * Cc * INNER, la_wkv + (size_t)i * Cc * 2 * INNER,
                       la_wo + (size_t)i * INNER * Cc, la_bo + i * Cc);

    hipLaunchKernelGGL(k_stats, dim3(NPOS / 4), dim3(256), 0, stream, xT, mean, rstd);
    hipLaunchKernelGGL(k_ff, dim3(NPOS / FR), dim3(256), 0, stream,
                       xT, mean, rstd, ln2_g + i * Cc, ln2_b + i * Cc,
                       ff1_w1 + (size_t)i * Cc * HID, ff1_b1 + i * HID,
                       ff1_w2 + (size_t)i * HID * Cc, ff1_b2 + i * Cc);

    hipLaunchKernelGGL(k_stats, dim3(NPOS / 4), dim3(256), 0, stream, xT, mean, rstd);
    hipLaunchKernelGGL(k_gkv, dim3(Bb * Vv * 3), dim3(256), 0, stream,
                       xT, mean, rstd, ln3_g + i * Cc, ln3_b + i * Cc,
                       ga_wkv + (size_t)i * Cc * Kk * 2 * INNER, kvg);
    hipLaunchKernelGGL(k_gattn, dim3(Bb * Vv * 10), dim3(256), 0, stream,
                       xT, mean, rstd, ln3_g + i * Cc, ln3_b + i * Cc,
                       ga_wq + (size_t)i * Cc * INNER, kvg,
                       ga_wo + (size_t)i * INNER * Cc, ga_bo + i * Cc);

    hipLaunchKernelGGL(k_stats, dim3(NPOS / 4), dim3(256), 0, stream, xT, mean, rstd);
    hipLaunchKernelGGL(k_ff, dim3(NPOS / FR), dim3(256), 0, stream,
                       xT, mean, rstd, ln4_g + i * Cc, ln4_b + i * Cc,
                       ff2_w1 + (size_t)i * Cc * HID, ff2_b1 + i * HID,
                       ff2_w2 + (size_t)i * HID * Cc, ff2_b2 + i * Cc);
  }

  // xT -> out (B,C,T,V)
  hipLaunchKernelGGL(k_transpose, dim3((Cc + 31) / 32, (TV + 31) / 32, Bb), blk2, 0, stream,
                     xT, (float*)d_out, TV, Cc);
}